// Round 1
// baseline (96.549 us; speedup 1.0000x reference)
//
#include <hip/hip_runtime.h>
#include <hip/hip_bf16.h>

#define NPTS 300
#define HW_SZ 1920
#define NH 8
#define ED2 128            // EMBED_DIM / 2
#define TOTAL (NPTS * HW_SZ)   // 576000
#define BLK 256

__global__ __launch_bounds__(BLK) void dre_kernel(
    const float* __restrict__ pd,   // (300,)
    const float* __restrict__ dm,   // (1920,) flattened (24,80)
    const float* __restrict__ W,    // (256, 8) row-major
    const float* __restrict__ b,    // (8,)
    float* __restrict__ out)        // (8, 300, 1920)
{
    __shared__ float kfreq[ED2];
    const int tid = threadIdx.x;
    if (tid < ED2) {
        // k_i = SCALE / dim_t[i] = 100 * 10000^(-i/128) = 100 * exp2(-i * log2(10000)/128)
        kfreq[tid] = 100.0f * exp2f(-(float)tid * (float)(13.287712379549449 / 128.0));
    }
    __syncthreads();

    const int idx = blockIdx.x * BLK + tid;
    const int n  = idx / HW_SZ;
    const int hw = idx - n * HW_SZ;

    const float pdv   = fmaxf(pd[n], 0.0f);
    const float delta = __logf((pdv + 1e-5f) / (dm[hw] + 1e-5f));

    float acc[NH];
#pragma unroll
    for (int h = 0; h < NH; ++h) acc[h] = b[h];   // uniform -> scalar loads

#pragma unroll 4
    for (int i = 0; i < ED2; ++i) {
        const float a = delta * kfreq[i];
        const float s = __sinf(a);
        const float c = __cosf(a);
        const float* wrow = W + i * 2 * NH;       // uniform index -> s_load
#pragma unroll
        for (int h = 0; h < NH; ++h) {
            acc[h] = fmaf(s, wrow[h],      acc[h]);
            acc[h] = fmaf(c, wrow[NH + h], acc[h]);
        }
    }

    const size_t base = (size_t)n * HW_SZ + hw;
#pragma unroll
    for (int h = 0; h < NH; ++h) {
        out[(size_t)h * TOTAL + base] = fmaxf(acc[h], 0.0f);
    }
}

extern "C" void kernel_launch(void* const* d_in, const int* in_sizes, int n_in,
                              void* d_out, int out_size, void* d_ws, size_t ws_size,
                              hipStream_t stream) {
    const float* pd = (const float*)d_in[0];
    const float* dm = (const float*)d_in[1];
    const float* W  = (const float*)d_in[2];
    const float* b  = (const float*)d_in[3];
    float* out = (float*)d_out;

    dre_kernel<<<TOTAL / BLK, BLK, 0, stream>>>(pd, dm, W, b, out);
}